// Round 12
// baseline (771.310 us; speedup 1.0000x reference)
//
#include <hip/hip_runtime.h>
#include <hip/hip_fp16.h>
#include <math.h>

#define D 128
#define CSH 13      // src-chunk shift: 8192 nodes/chunk -> 7 chunks at N=50000
#define BSH 9       // dst-bucket shift: 512 nodes/bucket -> 98 buckets
#define NB_MAX 128

typedef _Float16 f16;
typedef __attribute__((ext_vector_type(8))) _Float16 f16x8;
typedef __attribute__((ext_vector_type(4))) float f32x4;
typedef __attribute__((ext_vector_type(4))) int i32x4;

// ---------------- preprocessing: two-level binning ----------------

__global__ __launch_bounds__(256) void binA_count(
    const int* __restrict__ dst, int* __restrict__ bucketCount, int E)
{
    __shared__ int hist[NB_MAX];
    int tid = threadIdx.x;
    if (tid < NB_MAX) hist[tid] = 0;
    __syncthreads();
    int base = blockIdx.x * 4096;
    for (int i = tid; i < 4096; i += 256) {
        int e = base + i;
        if (e < E) atomicAdd(&hist[dst[e] >> BSH], 1);
    }
    __syncthreads();
    if (tid < NB_MAX && hist[tid]) atomicAdd(&bucketCount[tid], hist[tid]);
}

__global__ void bucket_scan(
    const int* __restrict__ bucketCount, int* __restrict__ bucketBase,
    int* __restrict__ bucketCursor, int* __restrict__ row_off,
    int NBUC, int E, int N)
{
    if (threadIdx.x == 0 && blockIdx.x == 0) {
        int p = 0;
        for (int b = 0; b < NBUC; ++b) {
            bucketBase[b] = p; bucketCursor[b] = p; p += bucketCount[b];
        }
        bucketBase[NBUC] = p;
        row_off[N] = E;
    }
}

__global__ __launch_bounds__(256) void binA_scatter(
    const int* __restrict__ src, const int* __restrict__ dst,
    const float* __restrict__ ew, int* __restrict__ bucketCursor,
    int4* __restrict__ binned, int E)
{
    __shared__ int hist[NB_MAX], off[NB_MAX], cbase[NB_MAX];
    int tid = threadIdx.x;
    if (tid < NB_MAX) { hist[tid] = 0; off[tid] = 0; }
    __syncthreads();
    int base = blockIdx.x * 4096;
    for (int i = tid; i < 4096; i += 256) {
        int e = base + i;
        if (e < E) atomicAdd(&hist[dst[e] >> BSH], 1);
    }
    __syncthreads();
    if (tid < NB_MAX && hist[tid])
        cbase[tid] = atomicAdd(&bucketCursor[tid], hist[tid]);
    __syncthreads();
    for (int i = tid; i < 4096; i += 256) {
        int e = base + i;
        if (e < E) {
            int d = dst[e];
            int b = d >> BSH;
            int pos = cbase[b] + atomicAdd(&off[b], 1);
            binned[pos] = make_int4(src[e], __float_as_int(ew[e]), d, 0);
        }
    }
}

__global__ __launch_bounds__(1024) void binB_kernel(
    const int4* __restrict__ binned, const int* __restrict__ bucketBase,
    int2* __restrict__ edge_s, int* __restrict__ row_off,
    float* __restrict__ sdeg, int N, int nchunk)
{
    __shared__ int hist[4096];
    __shared__ int cur[4096];
    __shared__ float sdl[512];
    __shared__ int wsum[16];

    int b    = blockIdx.x;
    int tid  = threadIdx.x;
    int ebeg = bucketBase[b], eend = bucketBase[b + 1];
    int node0 = b << BSH;
    int nib   = min(512, N - node0);

    for (int i = tid; i < 4096; i += 1024) hist[i] = 0;
    for (int i = tid; i < 512; i += 1024) sdl[i] = 0.f;
    __syncthreads();

    for (int e = ebeg + tid; e < eend; e += 1024) {
        int4 ed = binned[e];
        int dl = ed.z - node0;
        int ch = ((unsigned)ed.x) >> CSH;
        atomicAdd(&hist[dl * nchunk + ch], 1);
        atomicAdd(&sdl[dl], __int_as_float(ed.y));
    }
    __syncthreads();

    int t4 = tid * 4;
    int h0 = hist[t4], h1 = hist[t4 + 1], h2 = hist[t4 + 2], h3 = hist[t4 + 3];
    int sum = h0 + h1 + h2 + h3;
    int lane = tid & 63, wid = tid >> 6;
    int x = sum;
    #pragma unroll
    for (int o = 1; o < 64; o <<= 1) { int t = __shfl_up(x, o); if (lane >= o) x += t; }
    if (lane == 63) wsum[wid] = x;
    __syncthreads();
    if (tid < 16) {
        int y = wsum[tid];
        #pragma unroll
        for (int o = 1; o < 16; o <<= 1) { int t = __shfl_up(y, o, 16); if (tid >= o) y += t; }
        wsum[tid] = y;
    }
    __syncthreads();
    int excl = (wid ? wsum[wid - 1] : 0) + x - sum;
    cur[t4] = excl; cur[t4 + 1] = excl + h0;
    cur[t4 + 2] = excl + h0 + h1; cur[t4 + 3] = excl + h0 + h1 + h2;
    __syncthreads();

    for (int dl = tid; dl < nib; dl += 1024) {
        row_off[node0 + dl] = ebeg + cur[dl * nchunk];
        sdeg[node0 + dl]    = sdl[dl];
    }
    __syncthreads();

    for (int e = ebeg + tid; e < eend; e += 1024) {
        int4 ed = binned[e];
        int dl = ed.z - node0;
        int ch = ((unsigned)ed.x) >> CSH;
        int pos = ebeg + atomicAdd(&cur[dl * nchunk + ch], 1);
        edge_s[pos] = make_int2(ed.x, ed.y);
    }
}

// ---------------- W pack: f32 -> fp16 hi/lo in MFMA B-fragment order -----
__global__ __launch_bounds__(256) void pack_kernel(
    const float* __restrict__ W1, const float* __restrict__ W2,
    const float* __restrict__ W3, f16* __restrict__ Wp)
{
    int idx = blockIdx.x * 256 + threadIdx.x;   // 6144 total
    if (idx >= 6144) return;
    int lane = idx & 63;
    int t    = idx >> 6;       // 0..95
    int ks   = t & 3;
    int mot  = t >> 2;         // 0..23
    int m    = mot >> 3;
    int ot   = mot & 7;
    const float* W = (m == 0) ? W1 : (m == 1) ? W2 : W3;
    int o  = ot * 16 + (lane & 15);
    int kb = ks * 32 + (lane >> 4) * 8;
    f16x8 hi, lo;
    #pragma unroll
    for (int j = 0; j < 8; ++j) {
        float v = W[(size_t)o * D + kb + j];
        f16 hh = (f16)v;
        hi[j] = hh;
        lo[j] = (f16)(v - (float)hh);
    }
    size_t base = (size_t)ks * 24576 + (size_t)mot * 1024 + (size_t)lane * 8;
    *(f16x8*)&Wp[base]       = hi;
    *(f16x8*)&Wp[base + 512] = lo;
}

// ---------------- MFMA fused 3-matmul, W in registers --------------------

__global__ __launch_bounds__(256, 2) void gemm_kernel(
    const float* __restrict__ in, const f16* __restrict__ Wp,
    const float* __restrict__ b1, const float* __restrict__ b3,
    const float* __restrict__ sdeg, float* __restrict__ aA,
    float* __restrict__ aB, float* __restrict__ base_out,
    int N, int ntiles, int gridb)
{
    int tid  = threadIdx.x;
    int lane = tid & 63;
    int wid  = tid >> 6;
    int col  = lane & 15;
    int g    = lane >> 4;

    // W fragments: [m][oti][ks][hi/lo]
    f16x8 w[3][2][4][2];
    #pragma unroll
    for (int m = 0; m < 3; ++m)
        #pragma unroll
        for (int oti = 0; oti < 2; ++oti) {
            int mot = m * 8 + wid * 2 + oti;
            #pragma unroll
            for (int ks = 0; ks < 4; ++ks) {
                const f16* p = Wp + (size_t)ks * 24576 + (size_t)mot * 1024 + (size_t)lane * 8;
                w[m][oti][ks][0] = *(const f16x8*)p;
                w[m][oti][ks][1] = *(const f16x8*)(p + 512);
            }
        }

    float bi1[2], bi3[2];
    #pragma unroll
    for (int oti = 0; oti < 2; ++oti) {
        int o = (wid * 2 + oti) * 16 + col;
        bi1[oti] = b1[o];
        bi3[oti] = b3[o];
    }

    for (int t = blockIdx.x; t < ntiles; t += gridb) {
        int n0   = t * 16;
        int nrow = n0 + col;

        f32x4 acc[3][2];
        #pragma unroll
        for (int m = 0; m < 3; ++m)
            #pragma unroll
            for (int oti = 0; oti < 2; ++oti)
                acc[m][oti] = (f32x4){0.f, 0.f, 0.f, 0.f};

        #pragma unroll
        for (int ks = 0; ks < 4; ++ks) {
            float av[8];
            if (nrow < N) {
                float4 a0 = *(const float4*)&in[(size_t)nrow * D + ks * 32 + g * 8];
                float4 a1 = *(const float4*)&in[(size_t)nrow * D + ks * 32 + g * 8 + 4];
                av[0] = a0.x; av[1] = a0.y; av[2] = a0.z; av[3] = a0.w;
                av[4] = a1.x; av[5] = a1.y; av[6] = a1.z; av[7] = a1.w;
            } else {
                #pragma unroll
                for (int j = 0; j < 8; ++j) av[j] = 0.f;
            }
            f16x8 ahi, alo;
            #pragma unroll
            for (int j = 0; j < 8; ++j) {
                f16 hh = (f16)av[j];
                ahi[j] = hh;
                alo[j] = (f16)(av[j] - (float)hh);
            }
            #pragma unroll
            for (int m = 0; m < 3; ++m)
                #pragma unroll
                for (int oti = 0; oti < 2; ++oti) {
                    acc[m][oti] = __builtin_amdgcn_mfma_f32_16x16x32_f16(ahi, w[m][oti][ks][0], acc[m][oti], 0, 0, 0);
                    acc[m][oti] = __builtin_amdgcn_mfma_f32_16x16x32_f16(alo, w[m][oti][ks][0], acc[m][oti], 0, 0, 0);
                    acc[m][oti] = __builtin_amdgcn_mfma_f32_16x16x32_f16(ahi, w[m][oti][ks][1], acc[m][oti], 0, 0, 0);
                }
        }

        float* ah = (wid < 2) ? aA : aB;
        #pragma unroll
        for (int oti = 0; oti < 2; ++oti) {
            int o  = (wid * 2 + oti) * 16 + col;
            int oh = o & 63;
            #pragma unroll
            for (int r = 0; r < 4; ++r) {
                int node = n0 + g * 4 + r;
                if (node < N) {
                    float sv   = sdeg[node];
                    float aval = acc[0][oti][r] + bi1[oti];
                    float bval = acc[2][oti][r] + bi3[oti] - sv * acc[1][oti][r];
                    ah[(size_t)node * 64 + oh]     = aval;
                    base_out[(size_t)node * D + o] = bval;
                }
            }
        }
    }
}

// ---------------- CSR aggregate + activation (one 64-feature half) ------
// One wave per node; 24-edge pipelined batches; nontemporal streaming for
// edge meta / base / out so L2 stays dedicated to the aH gather lines.

__global__ __launch_bounds__(256, 3) void agg_kernel(
    const float* __restrict__ aH, const float* __restrict__ base,
    const int* __restrict__ row_off, const int2* __restrict__ edge_s,
    float* __restrict__ out, int N, int hofs, int last)
{
    int lane = threadIdx.x & 63;
    int node = blockIdx.x * 4 + (threadIdx.x >> 6);
    if (node >= N) return;

    float acc = __builtin_nontemporal_load(&base[(size_t)node * D + hofs + lane]);
    int beg = row_off[node];
    int end = row_off[node + 1];

    int e = beg;
    if ((e & 1) && e < end) {         // peel to align 16B batches
        int2 ed = edge_s[e];
        acc = fmaf(__int_as_float(ed.y), aH[(size_t)ed.x * 64 + lane], acc);
        ++e;
    }
    for (; e + 24 <= end; e += 24) {  // 24 edges: 12 vec4 meta + 24 gathers in flight
        i32x4 ed[12];
        #pragma unroll
        for (int i = 0; i < 12; ++i)
            ed[i] = __builtin_nontemporal_load((const i32x4*)&edge_s[e + i * 2]);
        float v[24];
        #pragma unroll
        for (int i = 0; i < 12; ++i) {
            v[2 * i]     = aH[(size_t)ed[i].x * 64 + lane];
            v[2 * i + 1] = aH[(size_t)ed[i].z * 64 + lane];
        }
        #pragma unroll
        for (int i = 0; i < 12; ++i) {
            acc = fmaf(__int_as_float(ed[i].y), v[2 * i], acc);
            acc = fmaf(__int_as_float(ed[i].w), v[2 * i + 1], acc);
        }
    }
    for (; e + 8 <= end; e += 8) {
        i32x4 ed[4];
        #pragma unroll
        for (int i = 0; i < 4; ++i)
            ed[i] = __builtin_nontemporal_load((const i32x4*)&edge_s[e + i * 2]);
        float v[8];
        #pragma unroll
        for (int i = 0; i < 4; ++i) {
            v[2 * i]     = aH[(size_t)ed[i].x * 64 + lane];
            v[2 * i + 1] = aH[(size_t)ed[i].z * 64 + lane];
        }
        #pragma unroll
        for (int i = 0; i < 4; ++i) {
            acc = fmaf(__int_as_float(ed[i].y), v[2 * i], acc);
            acc = fmaf(__int_as_float(ed[i].w), v[2 * i + 1], acc);
        }
    }
    for (; e < end; ++e) {
        int2 ed = edge_s[e];
        acc = fmaf(__int_as_float(ed.y), aH[(size_t)ed.x * 64 + lane], acc);
    }

    acc = acc >= 0.f ? acc : 0.1f * acc;          // leaky relu 0.1
    if (last) acc = 1.f / (1.f + __expf(-acc));   // sigmoid
    __builtin_nontemporal_store(acc, &out[(size_t)node * D + hofs + lane]);
}

// ---------------- launch ----------------

extern "C" void kernel_launch(void* const* d_in, const int* in_sizes, int n_in,
                              void* d_out, int out_size, void* d_ws, size_t ws_size,
                              hipStream_t stream) {
    const float* x   = (const float*)d_in[0];
    const int*   ei  = (const int*)d_in[1];
    const float* ew  = (const float*)d_in[2];
    const float* iW1 = (const float*)d_in[3];
    const float* ib1 = (const float*)d_in[4];
    const float* iW2 = (const float*)d_in[5];
    const float* iW3 = (const float*)d_in[6];
    const float* ib3 = (const float*)d_in[7];
    const float* mW1 = (const float*)d_in[8];
    const float* mb1 = (const float*)d_in[9];
    const float* mW2 = (const float*)d_in[10];
    const float* mW3 = (const float*)d_in[11];
    const float* mb3 = (const float*)d_in[12];
    const float* oW1 = (const float*)d_in[13];
    const float* ob1 = (const float*)d_in[14];
    const float* oW2 = (const float*)d_in[15];
    const float* oW3 = (const float*)d_in[16];
    const float* ob3 = (const float*)d_in[17];

    int N = in_sizes[0] / D;
    int E = in_sizes[2];
    const int* src = ei;
    const int* dst = ei + E;
    int nchunk = (N + (1 << CSH) - 1) >> CSH;   // 7
    int NBUC   = (N + (1 << BSH) - 1) >> BSH;   // 98

    char* wsp = (char*)d_ws;
    size_t off = 0;
    auto alloc = [&](size_t bytes) -> void* {
        void* p = wsp + off;
        off += (bytes + 255) & ~(size_t)255;
        return p;
    };
    float* h        = (float*)alloc((size_t)N * D * 4);   // aliased by binned
    float* base     = (float*)alloc((size_t)N * D * 4);
    float* aA       = (float*)alloc((size_t)N * 64 * 4);
    float* aB       = (float*)alloc((size_t)N * 64 * 4);
    float* sdeg     = (float*)alloc((size_t)N * 4);
    int*   row_off  = (int*)alloc((size_t)(N + 1) * 4);
    int2*  edge_s   = (int2*)alloc((size_t)E * 8);
    int*   bucketCount  = (int*)alloc((size_t)(NBUC + 1) * 4);
    int*   bucketBase   = (int*)alloc((size_t)(NBUC + 1) * 4);
    int*   bucketCursor = (int*)alloc((size_t)(NBUC + 1) * 4);
    f16*   Wp       = (f16*)alloc((size_t)3 * 98304 * 2);

    int4* binned = (int4*)h;

    hipMemsetAsync(bucketCount, 0, (size_t)(NBUC + 1) * 4, stream);

    int ablocks  = (N + 3) / 4;
    int ntiles   = (N + 15) / 16;
    int gridb    = 512;
    int abblocks = (E + 4095) / 4096;

    pack_kernel<<<24, 256, 0, stream>>>(iW1, iW2, iW3, Wp);
    pack_kernel<<<24, 256, 0, stream>>>(mW1, mW2, mW3, Wp + 98304);
    pack_kernel<<<24, 256, 0, stream>>>(oW1, oW2, oW3, Wp + 2 * 98304);

    binA_count<<<abblocks, 256, 0, stream>>>(dst, bucketCount, E);
    bucket_scan<<<1, 64, 0, stream>>>(bucketCount, bucketBase, bucketCursor,
                                      row_off, NBUC, E, N);
    binA_scatter<<<abblocks, 256, 0, stream>>>(src, dst, ew, bucketCursor,
                                               binned, E);
    binB_kernel<<<NBUC, 1024, 0, stream>>>(binned, bucketBase, edge_s,
                                           row_off, sdeg, N, nchunk);

    // layer 1 (in): reads x
    gemm_kernel<<<gridb, 256, 0, stream>>>(x, Wp, ib1, ib3, sdeg, aA, aB, base, N, ntiles, gridb);
    agg_kernel<<<ablocks, 256, 0, stream>>>(aA, base, row_off, edge_s, h, N, 0, 0);
    agg_kernel<<<ablocks, 256, 0, stream>>>(aB, base, row_off, edge_s, h, N, 64, 0);
    // layers 2..3 (mid, shared weights)
    for (int l = 0; l < 2; ++l) {
        gemm_kernel<<<gridb, 256, 0, stream>>>(h, Wp + 98304, mb1, mb3, sdeg, aA, aB, base, N, ntiles, gridb);
        agg_kernel<<<ablocks, 256, 0, stream>>>(aA, base, row_off, edge_s, h, N, 0, 0);
        agg_kernel<<<ablocks, 256, 0, stream>>>(aB, base, row_off, edge_s, h, N, 64, 0);
    }
    // layer 4 (out) -> d_out with sigmoid
    gemm_kernel<<<gridb, 256, 0, stream>>>(h, Wp + 2 * 98304, ob1, ob3, sdeg, aA, aB, base, N, ntiles, gridb);
    agg_kernel<<<ablocks, 256, 0, stream>>>(aA, base, row_off, edge_s, (float*)d_out, N, 0, 1);
    agg_kernel<<<ablocks, 256, 0, stream>>>(aB, base, row_off, edge_s, (float*)d_out, N, 64, 1);
}

// Round 13
// 678.470 us; speedup vs baseline: 1.1368x; 1.1368x over previous
//
#include <hip/hip_runtime.h>
#include <hip/hip_fp16.h>
#include <math.h>

#define D 128
#define CSH 13      // src-chunk shift: 8192 nodes/chunk -> 7 chunks at N=50000
#define BSH 9       // dst-bucket shift: 512 nodes/bucket -> 98 buckets
#define NB_MAX 128

typedef _Float16 f16;
typedef __attribute__((ext_vector_type(8))) _Float16 f16x8;
typedef __attribute__((ext_vector_type(4))) float f32x4;

// ---------------- preprocessing: two-level binning ----------------

__global__ __launch_bounds__(256) void binA_count(
    const int* __restrict__ dst, int* __restrict__ bucketCount, int E)
{
    __shared__ int hist[NB_MAX];
    int tid = threadIdx.x;
    if (tid < NB_MAX) hist[tid] = 0;
    __syncthreads();
    int base = blockIdx.x * 4096;
    for (int i = tid; i < 4096; i += 256) {
        int e = base + i;
        if (e < E) atomicAdd(&hist[dst[e] >> BSH], 1);
    }
    __syncthreads();
    if (tid < NB_MAX && hist[tid]) atomicAdd(&bucketCount[tid], hist[tid]);
}

__global__ void bucket_scan(
    const int* __restrict__ bucketCount, int* __restrict__ bucketBase,
    int* __restrict__ bucketCursor, int* __restrict__ row_off,
    int NBUC, int E, int N)
{
    if (threadIdx.x == 0 && blockIdx.x == 0) {
        int p = 0;
        for (int b = 0; b < NBUC; ++b) {
            bucketBase[b] = p; bucketCursor[b] = p; p += bucketCount[b];
        }
        bucketBase[NBUC] = p;
        row_off[N] = E;
    }
}

__global__ __launch_bounds__(256) void binA_scatter(
    const int* __restrict__ src, const int* __restrict__ dst,
    const float* __restrict__ ew, int* __restrict__ bucketCursor,
    int4* __restrict__ binned, int E)
{
    __shared__ int hist[NB_MAX], off[NB_MAX], cbase[NB_MAX];
    int tid = threadIdx.x;
    if (tid < NB_MAX) { hist[tid] = 0; off[tid] = 0; }
    __syncthreads();
    int base = blockIdx.x * 4096;
    for (int i = tid; i < 4096; i += 256) {
        int e = base + i;
        if (e < E) atomicAdd(&hist[dst[e] >> BSH], 1);
    }
    __syncthreads();
    if (tid < NB_MAX && hist[tid])
        cbase[tid] = atomicAdd(&bucketCursor[tid], hist[tid]);
    __syncthreads();
    for (int i = tid; i < 4096; i += 256) {
        int e = base + i;
        if (e < E) {
            int d = dst[e];
            int b = d >> BSH;
            int pos = cbase[b] + atomicAdd(&off[b], 1);
            binned[pos] = make_int4(src[e], __float_as_int(ew[e]), d, 0);
        }
    }
}

__global__ __launch_bounds__(1024) void binB_kernel(
    const int4* __restrict__ binned, const int* __restrict__ bucketBase,
    int2* __restrict__ edge_s, int* __restrict__ row_off,
    float* __restrict__ sdeg, int N, int nchunk)
{
    __shared__ int hist[4096];
    __shared__ int cur[4096];
    __shared__ float sdl[512];
    __shared__ int wsum[16];

    int b    = blockIdx.x;
    int tid  = threadIdx.x;
    int ebeg = bucketBase[b], eend = bucketBase[b + 1];
    int node0 = b << BSH;
    int nib   = min(512, N - node0);

    for (int i = tid; i < 4096; i += 1024) hist[i] = 0;
    for (int i = tid; i < 512; i += 1024) sdl[i] = 0.f;
    __syncthreads();

    for (int e = ebeg + tid; e < eend; e += 1024) {
        int4 ed = binned[e];
        int dl = ed.z - node0;
        int ch = ((unsigned)ed.x) >> CSH;
        atomicAdd(&hist[dl * nchunk + ch], 1);
        atomicAdd(&sdl[dl], __int_as_float(ed.y));
    }
    __syncthreads();

    int t4 = tid * 4;
    int h0 = hist[t4], h1 = hist[t4 + 1], h2 = hist[t4 + 2], h3 = hist[t4 + 3];
    int sum = h0 + h1 + h2 + h3;
    int lane = tid & 63, wid = tid >> 6;
    int x = sum;
    #pragma unroll
    for (int o = 1; o < 64; o <<= 1) { int t = __shfl_up(x, o); if (lane >= o) x += t; }
    if (lane == 63) wsum[wid] = x;
    __syncthreads();
    if (tid < 16) {
        int y = wsum[tid];
        #pragma unroll
        for (int o = 1; o < 16; o <<= 1) { int t = __shfl_up(y, o, 16); if (tid >= o) y += t; }
        wsum[tid] = y;
    }
    __syncthreads();
    int excl = (wid ? wsum[wid - 1] : 0) + x - sum;
    cur[t4] = excl; cur[t4 + 1] = excl + h0;
    cur[t4 + 2] = excl + h0 + h1; cur[t4 + 3] = excl + h0 + h1 + h2;
    __syncthreads();

    for (int dl = tid; dl < nib; dl += 1024) {
        row_off[node0 + dl] = ebeg + cur[dl * nchunk];
        sdeg[node0 + dl]    = sdl[dl];
    }
    __syncthreads();

    for (int e = ebeg + tid; e < eend; e += 1024) {
        int4 ed = binned[e];
        int dl = ed.z - node0;
        int ch = ((unsigned)ed.x) >> CSH;
        int pos = ebeg + atomicAdd(&cur[dl * nchunk + ch], 1);
        edge_s[pos] = make_int2(ed.x, ed.y);
    }
}

// ---------------- W pack: f32 -> fp16 hi/lo in MFMA B-fragment order -----
__global__ __launch_bounds__(256) void pack_kernel(
    const float* __restrict__ W1, const float* __restrict__ W2,
    const float* __restrict__ W3, f16* __restrict__ Wp)
{
    int idx = blockIdx.x * 256 + threadIdx.x;   // 6144 total
    if (idx >= 6144) return;
    int lane = idx & 63;
    int t    = idx >> 6;       // 0..95
    int ks   = t & 3;
    int mot  = t >> 2;         // 0..23
    int m    = mot >> 3;
    int ot   = mot & 7;
    const float* W = (m == 0) ? W1 : (m == 1) ? W2 : W3;
    int o  = ot * 16 + (lane & 15);
    int kb = ks * 32 + (lane >> 4) * 8;
    f16x8 hi, lo;
    #pragma unroll
    for (int j = 0; j < 8; ++j) {
        float v = W[(size_t)o * D + kb + j];
        f16 hh = (f16)v;
        hi[j] = hh;
        lo[j] = (f16)(v - (float)hh);
    }
    size_t base = (size_t)ks * 24576 + (size_t)mot * 1024 + (size_t)lane * 8;
    *(f16x8*)&Wp[base]       = hi;
    *(f16x8*)&Wp[base + 512] = lo;
}

// ---------------- MFMA fused 3-matmul, W in registers --------------------

__global__ __launch_bounds__(256, 2) void gemm_kernel(
    const float* __restrict__ in, const f16* __restrict__ Wp,
    const float* __restrict__ b1, const float* __restrict__ b3,
    const float* __restrict__ sdeg, float* __restrict__ aA,
    float* __restrict__ aB, float* __restrict__ base_out,
    int N, int ntiles, int gridb)
{
    int tid  = threadIdx.x;
    int lane = tid & 63;
    int wid  = tid >> 6;
    int col  = lane & 15;
    int g    = lane >> 4;

    // W fragments: [m][oti][ks][hi/lo]
    f16x8 w[3][2][4][2];
    #pragma unroll
    for (int m = 0; m < 3; ++m)
        #pragma unroll
        for (int oti = 0; oti < 2; ++oti) {
            int mot = m * 8 + wid * 2 + oti;
            #pragma unroll
            for (int ks = 0; ks < 4; ++ks) {
                const f16* p = Wp + (size_t)ks * 24576 + (size_t)mot * 1024 + (size_t)lane * 8;
                w[m][oti][ks][0] = *(const f16x8*)p;
                w[m][oti][ks][1] = *(const f16x8*)(p + 512);
            }
        }

    float bi1[2], bi3[2];
    #pragma unroll
    for (int oti = 0; oti < 2; ++oti) {
        int o = (wid * 2 + oti) * 16 + col;
        bi1[oti] = b1[o];
        bi3[oti] = b3[o];
    }

    for (int t = blockIdx.x; t < ntiles; t += gridb) {
        int n0   = t * 16;
        int nrow = n0 + col;

        f32x4 acc[3][2];
        #pragma unroll
        for (int m = 0; m < 3; ++m)
            #pragma unroll
            for (int oti = 0; oti < 2; ++oti)
                acc[m][oti] = (f32x4){0.f, 0.f, 0.f, 0.f};

        #pragma unroll
        for (int ks = 0; ks < 4; ++ks) {
            float av[8];
            if (nrow < N) {
                float4 a0 = *(const float4*)&in[(size_t)nrow * D + ks * 32 + g * 8];
                float4 a1 = *(const float4*)&in[(size_t)nrow * D + ks * 32 + g * 8 + 4];
                av[0] = a0.x; av[1] = a0.y; av[2] = a0.z; av[3] = a0.w;
                av[4] = a1.x; av[5] = a1.y; av[6] = a1.z; av[7] = a1.w;
            } else {
                #pragma unroll
                for (int j = 0; j < 8; ++j) av[j] = 0.f;
            }
            f16x8 ahi, alo;
            #pragma unroll
            for (int j = 0; j < 8; ++j) {
                f16 hh = (f16)av[j];
                ahi[j] = hh;
                alo[j] = (f16)(av[j] - (float)hh);
            }
            #pragma unroll
            for (int m = 0; m < 3; ++m)
                #pragma unroll
                for (int oti = 0; oti < 2; ++oti) {
                    acc[m][oti] = __builtin_amdgcn_mfma_f32_16x16x32_f16(ahi, w[m][oti][ks][0], acc[m][oti], 0, 0, 0);
                    acc[m][oti] = __builtin_amdgcn_mfma_f32_16x16x32_f16(alo, w[m][oti][ks][0], acc[m][oti], 0, 0, 0);
                    acc[m][oti] = __builtin_amdgcn_mfma_f32_16x16x32_f16(ahi, w[m][oti][ks][1], acc[m][oti], 0, 0, 0);
                }
        }

        float* ah = (wid < 2) ? aA : aB;
        #pragma unroll
        for (int oti = 0; oti < 2; ++oti) {
            int o  = (wid * 2 + oti) * 16 + col;
            int oh = o & 63;
            #pragma unroll
            for (int r = 0; r < 4; ++r) {
                int node = n0 + g * 4 + r;
                if (node < N) {
                    float sv   = sdeg[node];
                    float aval = acc[0][oti][r] + bi1[oti];
                    float bval = acc[2][oti][r] + bi3[oti] - sv * acc[1][oti][r];
                    ah[(size_t)node * 64 + oh]     = aval;
                    base_out[(size_t)node * D + o] = bval;
                }
            }
        }
    }
}

// ---------------- CSR aggregate + activation --------------------------
// One wave per node pair: TWO independent edge streams interleaved (2 dep
// chains -> 16 loads in flight). lanes 0-31 gather from aA, 32-63 from aB;
// each 32-lane group sweeps a full 256B row (coalesced).

__global__ __launch_bounds__(256) void agg_kernel(
    const float* __restrict__ aA, const float* __restrict__ aB,
    const float* __restrict__ base, const int* __restrict__ row_off,
    const int2* __restrict__ edge_s, float* __restrict__ out, int N, int last)
{
    int lane = threadIdx.x & 63;
    int wid  = threadIdx.x >> 6;
    int nA   = blockIdx.x * 8 + wid * 2;
    int nB   = nA + 1;
    if (nA >= N) return;
    bool hasB = (nB < N);

    const float* aH = (lane < 32) ? aA : aB;
    int fo = (lane & 31) * 2;     // feature offset within the 64-half
    int l2 = lane * 2;            // feature offset within 128

    float2 accA = *(const float2*)&base[(size_t)nA * D + l2];
    int eA = row_off[nA], endA = row_off[nA + 1];
    float2 accB = make_float2(0.f, 0.f);
    int eB = 0, endB = 0;
    if (hasB) {
        accB = *(const float2*)&base[(size_t)nB * D + l2];
        eB = row_off[nB]; endB = row_off[nB + 1];
    }

    // paired phase: 4 edges from each stream per iteration
    while (eA + 4 <= endA && eB + 4 <= endB) {
        int2 m[8];
        #pragma unroll
        for (int i = 0; i < 4; ++i) m[i] = edge_s[eA + i];
        #pragma unroll
        for (int i = 0; i < 4; ++i) m[4 + i] = edge_s[eB + i];
        float2 v[8];
        #pragma unroll
        for (int i = 0; i < 8; ++i)
            v[i] = *(const float2*)&aH[(size_t)m[i].x * 64 + fo];
        #pragma unroll
        for (int i = 0; i < 4; ++i) {
            float wgt = __int_as_float(m[i].y);
            accA.x = fmaf(wgt, v[i].x, accA.x);
            accA.y = fmaf(wgt, v[i].y, accA.y);
        }
        #pragma unroll
        for (int i = 0; i < 4; ++i) {
            float wgt = __int_as_float(m[4 + i].y);
            accB.x = fmaf(wgt, v[4 + i].x, accB.x);
            accB.y = fmaf(wgt, v[4 + i].y, accB.y);
        }
        eA += 4; eB += 4;
    }

    // single-stream finish (8-deep batches, then scalars)
    auto finish = [&](int e, int end, float2& acc) {
        for (; e + 8 <= end; e += 8) {
            int2 m[8];
            #pragma unroll
            for (int i = 0; i < 8; ++i) m[i] = edge_s[e + i];
            float2 v[8];
            #pragma unroll
            for (int i = 0; i < 8; ++i)
                v[i] = *(const float2*)&aH[(size_t)m[i].x * 64 + fo];
            #pragma unroll
            for (int i = 0; i < 8; ++i) {
                float wgt = __int_as_float(m[i].y);
                acc.x = fmaf(wgt, v[i].x, acc.x);
                acc.y = fmaf(wgt, v[i].y, acc.y);
            }
        }
        for (; e < end; ++e) {
            int2 m = edge_s[e];
            float2 v = *(const float2*)&aH[(size_t)m.x * 64 + fo];
            float wgt = __int_as_float(m.y);
            acc.x = fmaf(wgt, v.x, acc.x);
            acc.y = fmaf(wgt, v.y, acc.y);
        }
    };
    finish(eA, endA, accA);
    if (hasB) finish(eB, endB, accB);

    // epilogue
    accA.x = accA.x >= 0.f ? accA.x : 0.1f * accA.x;
    accA.y = accA.y >= 0.f ? accA.y : 0.1f * accA.y;
    if (last) {
        accA.x = 1.f / (1.f + __expf(-accA.x));
        accA.y = 1.f / (1.f + __expf(-accA.y));
    }
    *(float2*)&out[(size_t)nA * D + l2] = accA;
    if (hasB) {
        accB.x = accB.x >= 0.f ? accB.x : 0.1f * accB.x;
        accB.y = accB.y >= 0.f ? accB.y : 0.1f * accB.y;
        if (last) {
            accB.x = 1.f / (1.f + __expf(-accB.x));
            accB.y = 1.f / (1.f + __expf(-accB.y));
        }
        *(float2*)&out[(size_t)nB * D + l2] = accB;
    }
}

// ---------------- launch ----------------

extern "C" void kernel_launch(void* const* d_in, const int* in_sizes, int n_in,
                              void* d_out, int out_size, void* d_ws, size_t ws_size,
                              hipStream_t stream) {
    const float* x   = (const float*)d_in[0];
    const int*   ei  = (const int*)d_in[1];
    const float* ew  = (const float*)d_in[2];
    const float* iW1 = (const float*)d_in[3];
    const float* ib1 = (const float*)d_in[4];
    const float* iW2 = (const float*)d_in[5];
    const float* iW3 = (const float*)d_in[6];
    const float* ib3 = (const float*)d_in[7];
    const float* mW1 = (const float*)d_in[8];
    const float* mb1 = (const float*)d_in[9];
    const float* mW2 = (const float*)d_in[10];
    const float* mW3 = (const float*)d_in[11];
    const float* mb3 = (const float*)d_in[12];
    const float* oW1 = (const float*)d_in[13];
    const float* ob1 = (const float*)d_in[14];
    const float* oW2 = (const float*)d_in[15];
    const float* oW3 = (const float*)d_in[16];
    const float* ob3 = (const float*)d_in[17];

    int N = in_sizes[0] / D;
    int E = in_sizes[2];
    const int* src = ei;
    const int* dst = ei + E;
    int nchunk = (N + (1 << CSH) - 1) >> CSH;   // 7
    int NBUC   = (N + (1 << BSH) - 1) >> BSH;   // 98

    char* wsp = (char*)d_ws;
    size_t off = 0;
    auto alloc = [&](size_t bytes) -> void* {
        void* p = wsp + off;
        off += (bytes + 255) & ~(size_t)255;
        return p;
    };
    float* h        = (float*)alloc((size_t)N * D * 4);   // aliased by binned
    float* base     = (float*)alloc((size_t)N * D * 4);
    float* aA       = (float*)alloc((size_t)N * 64 * 4);
    float* aB       = (float*)alloc((size_t)N * 64 * 4);
    float* sdeg     = (float*)alloc((size_t)N * 4);
    int*   row_off  = (int*)alloc((size_t)(N + 1) * 4);
    int2*  edge_s   = (int2*)alloc((size_t)E * 8);
    int*   bucketCount  = (int*)alloc((size_t)(NBUC + 1) * 4);
    int*   bucketBase   = (int*)alloc((size_t)(NBUC + 1) * 4);
    int*   bucketCursor = (int*)alloc((size_t)(NBUC + 1) * 4);
    f16*   Wp       = (f16*)alloc((size_t)3 * 98304 * 2);

    int4* binned = (int4*)h;

    hipMemsetAsync(bucketCount, 0, (size_t)(NBUC + 1) * 4, stream);

    int ablocks  = (N + 7) / 8;
    int ntiles   = (N + 15) / 16;
    int gridb    = 512;
    int abblocks = (E + 4095) / 4096;

    pack_kernel<<<24, 256, 0, stream>>>(iW1, iW2, iW3, Wp);
    pack_kernel<<<24, 256, 0, stream>>>(mW1, mW2, mW3, Wp + 98304);
    pack_kernel<<<24, 256, 0, stream>>>(oW1, oW2, oW3, Wp + 2 * 98304);

    binA_count<<<abblocks, 256, 0, stream>>>(dst, bucketCount, E);
    bucket_scan<<<1, 64, 0, stream>>>(bucketCount, bucketBase, bucketCursor,
                                      row_off, NBUC, E, N);
    binA_scatter<<<abblocks, 256, 0, stream>>>(src, dst, ew, bucketCursor,
                                               binned, E);
    binB_kernel<<<NBUC, 1024, 0, stream>>>(binned, bucketBase, edge_s,
                                           row_off, sdeg, N, nchunk);

    // layer 1 (in): reads x
    gemm_kernel<<<gridb, 256, 0, stream>>>(x, Wp, ib1, ib3, sdeg, aA, aB, base, N, ntiles, gridb);
    agg_kernel<<<ablocks, 256, 0, stream>>>(aA, aB, base, row_off, edge_s, h, N, 0);
    // layers 2..3 (mid, shared weights)
    for (int l = 0; l < 2; ++l) {
        gemm_kernel<<<gridb, 256, 0, stream>>>(h, Wp + 98304, mb1, mb3, sdeg, aA, aB, base, N, ntiles, gridb);
        agg_kernel<<<ablocks, 256, 0, stream>>>(aA, aB, base, row_off, edge_s, h, N, 0);
    }
    // layer 4 (out) -> d_out with sigmoid
    gemm_kernel<<<gridb, 256, 0, stream>>>(h, Wp + 2 * 98304, ob1, ob3, sdeg, aA, aB, base, N, ntiles, gridb);
    agg_kernel<<<ablocks, 256, 0, stream>>>(aA, aB, base, row_off, edge_s, (float*)d_out, N, 1);
}